// Round 2
// baseline (602.390 us; speedup 1.0000x reference)
//
#include <hip/hip_runtime.h>
#include <stdint.h>

typedef unsigned short u16;
typedef __bf16 bf16x8 __attribute__((ext_vector_type(8)));
typedef float f32x4 __attribute__((ext_vector_type(4)));

#define SCALE_QK 0.125f

__device__ __forceinline__ u16 f2bf(float f) {
    uint32_t u = __builtin_bit_cast(uint32_t, f);
    u += 0x7FFFu + ((u >> 16) & 1u);
    return (u16)(u >> 16);
}

// floor(x/S) for S in {512, 576}; 576 = 64*9, magic div by 9.
__device__ __forceinline__ int bdiv(int x, int S) {
    return (S == 512) ? (x >> 9) : (int)(((uint64_t)(x >> 6) * 954437177ull) >> 33);
}

// ---------------- f32 -> bf16 convert ----------------
__global__ void cvt_f32_bf16(const float* __restrict__ src, u16* __restrict__ dst, int n4) {
    int i = blockIdx.x * blockDim.x + threadIdx.x;
    if (i >= n4) return;
    float4 v = ((const float4*)src)[i];
    ushort4 o;
    o.x = f2bf(v.x); o.y = f2bf(v.y); o.z = f2bf(v.z); o.w = f2bf(v.w);
    ((ushort4*)dst)[i] = o;
}

// ---------------- mask -> additive f32 bias ----------------
__global__ void mask_prep(const int* __restrict__ maski, float* __restrict__ mb, int n) {
    int i = blockIdx.x * blockDim.x + threadIdx.x;
    if (i >= n) return;
    int v0 = maski[0];
    int v = (v0 == 0x01010101) ? (int)((const unsigned char*)maski)[i] : maski[i];
    mb[i] = v ? 0.0f : -1e30f;
}

// ---------------- GEMM: C = A[M,K] * Bt[N,K]^T + bias ----------------
// LAYOUT 0: f32 row-major out [M][ldc], bias per col.
// LAYOUT 1: bf16 head-split QK out: part=col>>10, h=(col>>6)&15, d=col&63,
//           dest = out + part*partStride + ((b*16+h)*S + s)*64 + d. bias per col.
// LAYOUT 2: bf16 Vt out: row=dout (0..1023), col=global token idx b*S+s,
//           dest = out + ((b*16 + dout>>6)*64 + (dout&63))*S + s. bias per ROW.
__device__ __forceinline__ void gload_lds16(const void* g, void* l) {
    __builtin_amdgcn_global_load_lds(
        (__attribute__((address_space(1))) void*)(g),
        (__attribute__((address_space(3))) void*)(l), 16, 0, 0);
}

template<int LAYOUT>
__global__ __launch_bounds__(256)
void gemm_bt(const u16* __restrict__ A, const u16* __restrict__ Bt,
             const float* __restrict__ bias, void* __restrict__ Cout,
             int M, int N, int K, int ldc, int S, size_t partStride) {
    __shared__ u16 As[128 * 32];
    __shared__ u16 Bs[128 * 32];
    const int tid = threadIdx.x;
    const int wid = tid >> 6, lane = tid & 63;
    const int lo = lane & 15, hi = lane >> 4;
    const int wr = wid >> 1, wc = wid & 1;
    const int bm = blockIdx.y, bn = blockIdx.x;
    const u16* Ab = A + (size_t)bm * 128 * K;
    const u16* Bb = Bt + (size_t)bn * 128 * K;
    f32x4 acc[4][4] = {};
    for (int k0 = 0; k0 < K; k0 += 32) {
#pragma unroll
        for (int it = 0; it < 2; ++it) {
            int eo = it * 2048 + wid * 512 + lane * 8;
            int row = eo >> 5, kk = eo & 31;
            gload_lds16(Ab + (size_t)row * K + k0 + kk, As + it * 2048 + wid * 512);
            gload_lds16(Bb + (size_t)row * K + k0 + kk, Bs + it * 2048 + wid * 512);
        }
        __syncthreads();
        bf16x8 af[4], bfr[4];
        const int koff = hi * 8;
#pragma unroll
        for (int m = 0; m < 4; ++m)
            af[m] = *(const bf16x8*)(As + (wr * 64 + m * 16 + lo) * 32 + koff);
#pragma unroll
        for (int n = 0; n < 4; ++n)
            bfr[n] = *(const bf16x8*)(Bs + (wc * 64 + n * 16 + lo) * 32 + koff);
#pragma unroll
        for (int m = 0; m < 4; ++m)
#pragma unroll
            for (int n = 0; n < 4; ++n)
                acc[m][n] = __builtin_amdgcn_mfma_f32_16x16x32_bf16(af[m], bfr[n], acc[m][n], 0, 0, 0);
        __syncthreads();
    }
    const int rowbase = bm * 128 + wr * 64, colbase = bn * 128 + wc * 64;

    if (LAYOUT == 0) {
        float* C = (float*)Cout;
#pragma unroll
        for (int m = 0; m < 4; ++m)
#pragma unroll
            for (int r = 0; r < 4; ++r) {
                int row = rowbase + m * 16 + hi * 4 + r;
#pragma unroll
                for (int n = 0; n < 4; ++n) {
                    int col = colbase + n * 16 + lo;
                    C[(size_t)row * ldc + col] = acc[m][n][r] + bias[col];
                }
            }
    } else if (LAYOUT == 1) {
        const int part = colbase >> 10;
        const int h = (colbase >> 6) & 15;
        u16* base = (u16*)Cout + (size_t)part * partStride;
        float bv[4];
#pragma unroll
        for (int n = 0; n < 4; ++n) bv[n] = bias[colbase + n * 16 + lo];
#pragma unroll
        for (int m = 0; m < 4; ++m)
#pragma unroll
            for (int r = 0; r < 4; ++r) {
                int row = rowbase + m * 16 + hi * 4 + r;
                int b = bdiv(row, S);
                int s = row - b * S;
                u16* rp = base + (((size_t)(b * 16 + h) * S + s) << 6);
#pragma unroll
                for (int n = 0; n < 4; ++n)
                    rp[n * 16 + lo] = f2bf(acc[m][n][r] + bv[n]);
            }
    } else {
        u16* base = (u16*)Cout;
        int bn_[4], s0_[4];
#pragma unroll
        for (int n = 0; n < 4; ++n) {
            int col0 = colbase + n * 16;
            int b = bdiv(col0, S);
            bn_[n] = b;
            s0_[n] = col0 - b * S;
        }
#pragma unroll
        for (int m = 0; m < 4; ++m)
#pragma unroll
            for (int r = 0; r < 4; ++r) {
                int dout = rowbase + m * 16 + hi * 4 + r;
                float bv = bias[dout];
                size_t hd = (size_t)(dout >> 6) * 64 + (dout & 63);
#pragma unroll
                for (int n = 0; n < 4; ++n)
                    base[((size_t)(bn_[n] * 16) * 64 + hd) * S + s0_[n] + lo] =
                        f2bf(acc[m][n][r] + bv);
            }
    }
}

// ---------------- fused flash attention v2 ----------------
// Q,K: [B][H][S][64] bf16 head-split.  Vt: [B][H][64][Sk] bf16.
// Out: merged [B*Sq][1024] bf16. Grid (Sq/64, B*H), 4 waves x 16 q rows, 64-key chunks.
template<int MASKED>
__global__ __launch_bounds__(256)
void attn_v2(const u16* __restrict__ Q, const u16* __restrict__ Kb,
             const u16* __restrict__ Vt, const float* __restrict__ mb,
             u16* __restrict__ Out, int Sq, int Sk) {
    __shared__ u16 p_lds[4][16 * 72];
    const int tid = threadIdx.x, wid = tid >> 6, lane = tid & 63;
    const int lo = lane & 15, hi = lane >> 4;
    const int b = blockIdx.y >> 4, h = blockIdx.y & 15;
    const int bh = blockIdx.y;
    const int q0 = blockIdx.x * 64 + wid * 16;
    const u16* Qp = Q + ((size_t)bh * Sq + q0) * 64;
    const u16* Kp = Kb + (size_t)bh * Sk * 64;
    const u16* Vp = Vt + (size_t)bh * 64 * Sk;
    bf16x8 qf[2];
#pragma unroll
    for (int ks = 0; ks < 2; ++ks)
        qf[ks] = *(const bf16x8*)(Qp + lo * 64 + ks * 32 + hi * 8);
    f32x4 oacc[4] = {};
    float mrow[4], lrow[4];
#pragma unroll
    for (int r = 0; r < 4; ++r) { mrow[r] = -3e38f; lrow[r] = 0.f; }
    u16* pl = p_lds[wid];
    for (int c0 = 0; c0 < Sk; c0 += 64) {
        float sc[4][4];
#pragma unroll
        for (int kt = 0; kt < 4; ++kt) {
            const u16* kp = Kp + (size_t)(c0 + kt * 16 + lo) * 64 + hi * 8;
            bf16x8 kf0 = *(const bf16x8*)(kp);
            bf16x8 kf1 = *(const bf16x8*)(kp + 32);
            f32x4 z = {};
            z = __builtin_amdgcn_mfma_f32_16x16x32_bf16(qf[0], kf0, z, 0, 0, 0);
            z = __builtin_amdgcn_mfma_f32_16x16x32_bf16(qf[1], kf1, z, 0, 0, 0);
            float mbv = 0.f;
            if (MASKED) mbv = mb[b * Sk + c0 + kt * 16 + lo];
#pragma unroll
            for (int r = 0; r < 4; ++r) sc[kt][r] = z[r] * SCALE_QK + mbv;
        }
        float alpha[4];
#pragma unroll
        for (int r = 0; r < 4; ++r) {
            float v = fmaxf(fmaxf(sc[0][r], sc[1][r]), fmaxf(sc[2][r], sc[3][r]));
            v = fmaxf(v, __shfl_xor(v, 1));
            v = fmaxf(v, __shfl_xor(v, 2));
            v = fmaxf(v, __shfl_xor(v, 4));
            v = fmaxf(v, __shfl_xor(v, 8));
            float mn = fmaxf(mrow[r], v);
            alpha[r] = __expf(mrow[r] - mn);
            mrow[r] = mn;
        }
#pragma unroll
        for (int r = 0; r < 4; ++r) {
            float sum = 0.f;
#pragma unroll
            for (int kt = 0; kt < 4; ++kt) {
                float p = __expf(sc[kt][r] - mrow[r]);
                sc[kt][r] = p;
                sum += p;
            }
            sum += __shfl_xor(sum, 1);
            sum += __shfl_xor(sum, 2);
            sum += __shfl_xor(sum, 4);
            sum += __shfl_xor(sum, 8);
            lrow[r] = lrow[r] * alpha[r] + sum;
        }
#pragma unroll
        for (int n = 0; n < 4; ++n)
#pragma unroll
            for (int r = 0; r < 4; ++r) oacc[n][r] *= alpha[r];
        // P -> per-wave LDS [16][72] (padded); in-wave DS ordering, no barrier.
#pragma unroll
        for (int kt = 0; kt < 4; ++kt)
#pragma unroll
            for (int r = 0; r < 4; ++r)
                pl[(hi * 4 + r) * 72 + kt * 16 + lo] = f2bf(sc[kt][r]);
        bf16x8 pf0 = *(const bf16x8*)(pl + lo * 72 + hi * 8);
        bf16x8 pf1 = *(const bf16x8*)(pl + lo * 72 + 32 + hi * 8);
#pragma unroll
        for (int n = 0; n < 4; ++n) {
            const u16* vp = Vp + (size_t)(n * 16 + lo) * Sk + c0 + hi * 8;
            bf16x8 v0 = *(const bf16x8*)(vp);
            bf16x8 v1 = *(const bf16x8*)(vp + 32);
            oacc[n] = __builtin_amdgcn_mfma_f32_16x16x32_bf16(pf0, v0, oacc[n], 0, 0, 0);
            oacc[n] = __builtin_amdgcn_mfma_f32_16x16x32_bf16(pf1, v1, oacc[n], 0, 0, 0);
        }
    }
    float inv[4];
#pragma unroll
    for (int r = 0; r < 4; ++r) inv[r] = 1.0f / lrow[r];
    u16* op = Out + ((size_t)(b * Sq + blockIdx.x * 64 + wid * 16)) * 1024 + h * 64;
#pragma unroll
    for (int n = 0; n < 4; ++n)
#pragma unroll
        for (int r = 0; r < 4; ++r)
            op[(size_t)(hi * 4 + r) * 1024 + n * 16 + lo] = f2bf(oacc[n][r] * inv[r]);
}

// ---------------- host ----------------
extern "C" void kernel_launch(void* const* d_in, const int* in_sizes, int n_in,
                              void* d_out, int out_size, void* d_ws, size_t ws_size,
                              hipStream_t stream) {
    (void)in_sizes; (void)n_in; (void)out_size; (void)ws_size;
    const float* text  = (const float*)d_in[0];
    const float* image = (const float*)d_in[1];
    const int*   maski = (const int*)d_in[2];
    const float* w_qt = (const float*)d_in[3];  const float* b_qt = (const float*)d_in[4];
    const float* w_ki = (const float*)d_in[5];  const float* b_ki = (const float*)d_in[6];
    const float* w_vi = (const float*)d_in[7];  const float* b_vi = (const float*)d_in[8];
    const float* w_qi = (const float*)d_in[9];  const float* b_qi = (const float*)d_in[10];
    const float* w_kt = (const float*)d_in[11]; const float* b_kt = (const float*)d_in[12];
    const float* w_vt = (const float*)d_in[13]; const float* b_vt = (const float*)d_in[14];
    const float* w_ot = (const float*)d_in[15]; const float* b_ot = (const float*)d_in[16];
    const float* w_oi = (const float*)d_in[17]; const float* b_oi = (const float*)d_in[18];

    const int B = 16, T = 512, P = 576, D = 1024;
    const int MT = B * T;   // 8192
    const int MI = B * P;   // 9216

    char* wp = (char*)d_ws;
    auto alloc = [&](size_t bytes) { char* r = wp; wp += (bytes + 255) & ~(size_t)255; return r; };
    u16* Xt    = (u16*)alloc((size_t)MT * D * 2);        // also reused as AttT
    u16* Xi    = (u16*)alloc((size_t)MI * D * 2);        // also reused as AttI
    u16* Wqk_t = (u16*)alloc((size_t)2 * D * D * 2);
    u16* Wqk_i = (u16*)alloc((size_t)2 * D * D * 2);
    u16* Wv_t  = (u16*)alloc((size_t)D * D * 2);
    u16* Wv_i  = (u16*)alloc((size_t)D * D * 2);
    u16* Wot   = (u16*)alloc((size_t)D * D * 2);
    u16* Woi   = (u16*)alloc((size_t)D * D * 2);
    float* bqk_t = (float*)alloc((size_t)2 * D * 4);
    float* bqk_i = (float*)alloc((size_t)2 * D * 4);
    float* mbf   = (float*)alloc((size_t)B * T * 4);
    u16* QKt  = (u16*)alloc((size_t)2 * MT * D * 2);     // Q_t then K_t, head-split
    u16* QKi  = (u16*)alloc((size_t)2 * MI * D * 2);     // Q_i then K_i
    u16* Vtt  = (u16*)alloc((size_t)MT * D * 2);         // Vt of text  [B][16][64][512]
    u16* Vti  = (u16*)alloc((size_t)MI * D * 2);         // Vt of image [B][16][64][576]

    auto cvt = [&](const float* s, u16* d, size_t n) {
        int n4 = (int)(n / 4);
        cvt_f32_bf16<<<(n4 + 255) / 256, 256, 0, stream>>>(s, d, n4);
    };
    cvt(text, Xt, (size_t)MT * D);
    cvt(image, Xi, (size_t)MI * D);
    cvt(w_qt, Wqk_t,                 (size_t)D * D);
    cvt(w_kt, Wqk_t + (size_t)D * D, (size_t)D * D);
    cvt(w_qi, Wqk_i,                 (size_t)D * D);
    cvt(w_ki, Wqk_i + (size_t)D * D, (size_t)D * D);
    cvt(w_vt, Wv_t, (size_t)D * D);
    cvt(w_vi, Wv_i, (size_t)D * D);
    cvt(w_ot, Wot,  (size_t)D * D);
    cvt(w_oi, Woi,  (size_t)D * D);
    hipMemcpyAsync(bqk_t,     b_qt, D * 4, hipMemcpyDeviceToDevice, stream);
    hipMemcpyAsync(bqk_t + D, b_kt, D * 4, hipMemcpyDeviceToDevice, stream);
    hipMemcpyAsync(bqk_i,     b_qi, D * 4, hipMemcpyDeviceToDevice, stream);
    hipMemcpyAsync(bqk_i + D, b_ki, D * 4, hipMemcpyDeviceToDevice, stream);
    mask_prep<<<(B * T + 255) / 256, 256, 0, stream>>>(maski, mbf, B * T);

    // QK projections -> head-split Q,K
    gemm_bt<1><<<dim3(2 * D / 128, MT / 128), 256, 0, stream>>>(
        Xt, Wqk_t, bqk_t, QKt, MT, 2 * D, D, 0, T, (size_t)MT * D);
    gemm_bt<1><<<dim3(2 * D / 128, MI / 128), 256, 0, stream>>>(
        Xi, Wqk_i, bqk_i, QKi, MI, 2 * D, D, 0, P, (size_t)MI * D);
    // V projections as swapped GEMM -> transposed Vt directly
    gemm_bt<2><<<dim3(MT / 128, D / 128), 256, 0, stream>>>(
        Wv_t, Xt, b_vt, Vtt, D, MT, D, 0, T, 0);
    gemm_bt<2><<<dim3(MI / 128, D / 128), 256, 0, stream>>>(
        Wv_i, Xi, b_vi, Vti, D, MI, D, 0, P, 0);

    // text attends to image (no mask); image attends to text (masked text keys)
    attn_v2<0><<<dim3(T / 64, B * 16), 256, 0, stream>>>(
        QKt, QKi + (size_t)MI * D, Vti, nullptr, Xt, T, P);
    attn_v2<1><<<dim3(P / 64, B * 16), 256, 0, stream>>>(
        QKi, QKt + (size_t)MT * D, Vtt, mbf, Xi, P, T);

    // output projections (f32 out + bias)
    gemm_bt<0><<<dim3(D / 128, MT / 128), 256, 0, stream>>>(
        Xt, Wot, b_ot, d_out, MT, D, D, D, T, 0);
    gemm_bt<0><<<dim3(D / 128, MI / 128), 256, 0, stream>>>(
        Xi, Woi, b_oi, (void*)((float*)d_out + (size_t)MT * D), MI, D, D, D, P, 0);
}

// Round 3
// 457.392 us; speedup vs baseline: 1.3170x; 1.3170x over previous
//
#include <hip/hip_runtime.h>
#include <stdint.h>

typedef unsigned short u16;
typedef __bf16 bf16x8 __attribute__((ext_vector_type(8)));
typedef float f32x4 __attribute__((ext_vector_type(4)));

#define SCALE_QK 0.125f

__device__ __forceinline__ u16 f2bf(float f) {
    uint32_t u = __builtin_bit_cast(uint32_t, f);
    u += 0x7FFFu + ((u >> 16) & 1u);
    return (u16)(u >> 16);
}

__device__ __forceinline__ int bdiv(int x, int S) {
    return (S == 512) ? (x >> 9) : (int)(((uint64_t)(x >> 6) * 954437177ull) >> 33);
}

// ---------------- f32 -> bf16 convert ----------------
__global__ void cvt_f32_bf16(const float* __restrict__ src, u16* __restrict__ dst, int n4) {
    int i = blockIdx.x * blockDim.x + threadIdx.x;
    if (i >= n4) return;
    float4 v = ((const float4*)src)[i];
    ushort4 o;
    o.x = f2bf(v.x); o.y = f2bf(v.y); o.z = f2bf(v.z); o.w = f2bf(v.w);
    ((ushort4*)dst)[i] = o;
}

// ---------------- mask -> additive f32 bias ----------------
__global__ void mask_prep(const int* __restrict__ maski, float* __restrict__ mb, int n) {
    int i = blockIdx.x * blockDim.x + threadIdx.x;
    if (i >= n) return;
    int v0 = maski[0];
    int v = (v0 == 0x01010101) ? (int)((const unsigned char*)maski)[i] : maski[i];
    mb[i] = v ? 0.0f : -1e30f;
}

// ---------------- GEMM: C = A[M,K] * Bt[N,K]^T + bias (m97 structure) ----------------
__device__ __forceinline__ void gload_lds16(const void* g, void* l) {
    __builtin_amdgcn_global_load_lds(
        (__attribute__((address_space(1))) void*)(g),
        (__attribute__((address_space(3))) void*)(l), 16, 0, 0);
}

template<int LAYOUT>
__global__ __launch_bounds__(256)
void gemm_bt(const u16* __restrict__ A, const u16* __restrict__ Bt,
             const float* __restrict__ bias, void* __restrict__ Cout,
             int M, int N, int K, int ldc, int S, size_t partStride) {
    __shared__ u16 As[128 * 32];
    __shared__ u16 Bs[128 * 32];
    const int tid = threadIdx.x;
    const int wid = tid >> 6, lane = tid & 63;
    const int lo = lane & 15, hi = lane >> 4;
    const int wr = wid >> 1, wc = wid & 1;
    const int bm = blockIdx.y, bn = blockIdx.x;
    const u16* Ab = A + (size_t)bm * 128 * K;
    const u16* Bb = Bt + (size_t)bn * 128 * K;
    f32x4 acc[4][4] = {};
    for (int k0 = 0; k0 < K; k0 += 32) {
#pragma unroll
        for (int it = 0; it < 2; ++it) {
            int eo = it * 2048 + wid * 512 + lane * 8;
            int row = eo >> 5, kk = eo & 31;
            gload_lds16(Ab + (size_t)row * K + k0 + kk, As + it * 2048 + wid * 512);
            gload_lds16(Bb + (size_t)row * K + k0 + kk, Bs + it * 2048 + wid * 512);
        }
        __syncthreads();
        bf16x8 af[4], bfr[4];
        const int koff = hi * 8;
#pragma unroll
        for (int m = 0; m < 4; ++m)
            af[m] = *(const bf16x8*)(As + (wr * 64 + m * 16 + lo) * 32 + koff);
#pragma unroll
        for (int n = 0; n < 4; ++n)
            bfr[n] = *(const bf16x8*)(Bs + (wc * 64 + n * 16 + lo) * 32 + koff);
#pragma unroll
        for (int m = 0; m < 4; ++m)
#pragma unroll
            for (int n = 0; n < 4; ++n)
                acc[m][n] = __builtin_amdgcn_mfma_f32_16x16x32_bf16(af[m], bfr[n], acc[m][n], 0, 0, 0);
        __syncthreads();
    }
    const int rowbase = bm * 128 + wr * 64, colbase = bn * 128 + wc * 64;

    if (LAYOUT == 0) {
        float* C = (float*)Cout;
#pragma unroll
        for (int m = 0; m < 4; ++m)
#pragma unroll
            for (int r = 0; r < 4; ++r) {
                int row = rowbase + m * 16 + hi * 4 + r;
#pragma unroll
                for (int n = 0; n < 4; ++n) {
                    int col = colbase + n * 16 + lo;
                    C[(size_t)row * ldc + col] = acc[m][n][r] + bias[col];
                }
            }
    } else if (LAYOUT == 1) {
        const int part = colbase >> 10;
        const int h = (colbase >> 6) & 15;
        u16* base = (u16*)Cout + (size_t)part * partStride;
        float bv[4];
#pragma unroll
        for (int n = 0; n < 4; ++n) bv[n] = bias[colbase + n * 16 + lo];
#pragma unroll
        for (int m = 0; m < 4; ++m)
#pragma unroll
            for (int r = 0; r < 4; ++r) {
                int row = rowbase + m * 16 + hi * 4 + r;
                int b = bdiv(row, S);
                int s = row - b * S;
                u16* rp = base + (((size_t)(b * 16 + h) * S + s) << 6);
#pragma unroll
                for (int n = 0; n < 4; ++n)
                    rp[n * 16 + lo] = f2bf(acc[m][n][r] + bv[n]);
            }
    } else {
        u16* base = (u16*)Cout;
        int bn_[4], s0_[4];
#pragma unroll
        for (int n = 0; n < 4; ++n) {
            int col0 = colbase + n * 16;
            int b = bdiv(col0, S);
            bn_[n] = b;
            s0_[n] = col0 - b * S;
        }
#pragma unroll
        for (int m = 0; m < 4; ++m)
#pragma unroll
            for (int r = 0; r < 4; ++r) {
                int dout = rowbase + m * 16 + hi * 4 + r;
                float bv = bias[dout];
                size_t hd = (size_t)(dout >> 6) * 64 + (dout & 63);
#pragma unroll
                for (int n = 0; n < 4; ++n)
                    base[((size_t)(bn_[n] * 16) * 64 + hd) * S + s0_[n] + lo] =
                        f2bf(acc[m][n][r] + bv);
            }
    }
}

// ---------------- fused flash attention v3: LDS-staged K/V, double-buffered ----------------
// Q,K: [B][H][Sq][64] bf16. Vt: [B][H][64][Sk] bf16. Out merged [B*Sq][1024] bf16.
// Grid 1D = NQ*256 blocks, XCD-swizzled so blocks sharing (b,h) land on one XCD.
// Block: 4 waves x 16 q-rows = 64 q-rows. K/V chunks of 64 keys staged in LDS
// (XOR-swizzled: slot ^= row&7 on 16B slots) with global_load_lds, 2-phase dbuf.
template<int MASKED, int NQ, int SK>
__global__ __launch_bounds__(256)
void attn_v3(const u16* __restrict__ Q, const u16* __restrict__ Kb,
             const u16* __restrict__ Vt, const float* __restrict__ mb,
             u16* __restrict__ Out) {
    constexpr int SQ = NQ * 64;
    constexpr int NC = SK / 64;
    __shared__ u16 kls[2][64 * 64];
    __shared__ u16 vls[2][64 * 64];
    __shared__ u16 pls[4][16 * 72];
    const int tid = threadIdx.x, wid = tid >> 6, lane = tid & 63;
    const int lo = lane & 15, hi = lane >> 4;
    // XCD swizzle: nwg = NQ*256, divisible by 8.
    const int id = blockIdx.x;
    const int f = (id & 7) * (NQ * 32) + (id >> 3);
    const int qc = f % NQ, bh = f / NQ;
    const int b = bh >> 4, h = bh & 15;
    const int q0 = qc * 64 + wid * 16;
    const u16* Qp = Q + ((size_t)bh * SQ + q0) * 64;
    const u16* Kp = Kb + (size_t)bh * SK * 64;
    const u16* Vp = Vt + (size_t)bh * 64 * SK;

    bf16x8 qf[2];
#pragma unroll
    for (int ks = 0; ks < 2; ++ks)
        qf[ks] = *(const bf16x8*)(Qp + lo * 64 + ks * 32 + hi * 8);

    f32x4 oacc[4] = {};
    float mrow[4], lrow[4];
#pragma unroll
    for (int r = 0; r < 4; ++r) { mrow[r] = -3e38f; lrow[r] = 0.f; }
    u16* pl = pls[wid];

    auto stage = [&](int bufi, int c0) {
#pragma unroll
        for (int j = 0; j < 2; ++j) {
            const int beta = (j * 4 + wid) * 64 + lane;     // 16B-block index
            const int row = beta >> 3, slot = beta & 7;
            const int e = (slot ^ (row & 7)) << 3;           // swizzled element col
            gload_lds16(Kp + (size_t)(c0 + row) * 64 + e,
                        &kls[bufi][0] + (j * 4 + wid) * 512);
            gload_lds16(Vp + (size_t)row * SK + c0 + e,
                        &vls[bufi][0] + (j * 4 + wid) * 512);
        }
    };

    stage(0, 0);
    __syncthreads();

    for (int c = 0; c < NC; ++c) {
        const int c0 = c * 64;
        if (c + 1 < NC) stage((c + 1) & 1, c0 + 64);
        const u16* kb = &kls[c & 1][0];
        const u16* vb = &vls[c & 1][0];

        float sc[4][4];
#pragma unroll
        for (int kt = 0; kt < 4; ++kt) {
            const int r = kt * 16 + lo;
            const int rx = r & 7;
            bf16x8 kf0 = *(const bf16x8*)(kb + r * 64 + ((hi ^ rx) << 3));
            bf16x8 kf1 = *(const bf16x8*)(kb + r * 64 + (((4 + hi) ^ rx) << 3));
            f32x4 z = {};
            z = __builtin_amdgcn_mfma_f32_16x16x32_bf16(qf[0], kf0, z, 0, 0, 0);
            z = __builtin_amdgcn_mfma_f32_16x16x32_bf16(qf[1], kf1, z, 0, 0, 0);
            float mbv = 0.f;
            if (MASKED) mbv = mb[b * SK + c0 + kt * 16 + lo];
#pragma unroll
            for (int rr = 0; rr < 4; ++rr) sc[kt][rr] = z[rr] * SCALE_QK + mbv;
        }
        float alpha[4];
#pragma unroll
        for (int r = 0; r < 4; ++r) {
            float v = fmaxf(fmaxf(sc[0][r], sc[1][r]), fmaxf(sc[2][r], sc[3][r]));
            v = fmaxf(v, __shfl_xor(v, 1));
            v = fmaxf(v, __shfl_xor(v, 2));
            v = fmaxf(v, __shfl_xor(v, 4));
            v = fmaxf(v, __shfl_xor(v, 8));
            float mn = fmaxf(mrow[r], v);
            alpha[r] = __expf(mrow[r] - mn);
            mrow[r] = mn;
        }
#pragma unroll
        for (int r = 0; r < 4; ++r) {
            float sum = 0.f;
#pragma unroll
            for (int kt = 0; kt < 4; ++kt) {
                float p = __expf(sc[kt][r] - mrow[r]);
                sc[kt][r] = p;
                sum += p;
            }
            sum += __shfl_xor(sum, 1);
            sum += __shfl_xor(sum, 2);
            sum += __shfl_xor(sum, 4);
            sum += __shfl_xor(sum, 8);
            lrow[r] = lrow[r] * alpha[r] + sum;
        }
#pragma unroll
        for (int n = 0; n < 4; ++n)
#pragma unroll
            for (int r = 0; r < 4; ++r) oacc[n][r] *= alpha[r];
        // P round-trip via per-wave LDS (C-frag -> A-frag)
#pragma unroll
        for (int kt = 0; kt < 4; ++kt)
#pragma unroll
            for (int r = 0; r < 4; ++r)
                pl[(hi * 4 + r) * 72 + kt * 16 + lo] = f2bf(sc[kt][r]);
        bf16x8 pf0 = *(const bf16x8*)(pl + lo * 72 + hi * 8);
        bf16x8 pf1 = *(const bf16x8*)(pl + lo * 72 + 32 + hi * 8);
#pragma unroll
        for (int n = 0; n < 4; ++n) {
            const int d = n * 16 + lo;
            const int dx = d & 7;
            bf16x8 v0 = *(const bf16x8*)(vb + d * 64 + ((hi ^ dx) << 3));
            bf16x8 v1 = *(const bf16x8*)(vb + d * 64 + (((4 + hi) ^ dx) << 3));
            oacc[n] = __builtin_amdgcn_mfma_f32_16x16x32_bf16(pf0, v0, oacc[n], 0, 0, 0);
            oacc[n] = __builtin_amdgcn_mfma_f32_16x16x32_bf16(pf1, v1, oacc[n], 0, 0, 0);
        }
        __syncthreads();
    }
    float inv[4];
#pragma unroll
    for (int r = 0; r < 4; ++r) inv[r] = 1.0f / lrow[r];
    u16* op = Out + ((size_t)(b * SQ + q0)) * 1024 + h * 64;
#pragma unroll
    for (int n = 0; n < 4; ++n)
#pragma unroll
        for (int r = 0; r < 4; ++r)
            op[(size_t)(hi * 4 + r) * 1024 + n * 16 + lo] = f2bf(oacc[n][r] * inv[r]);
}

// ---------------- host ----------------
extern "C" void kernel_launch(void* const* d_in, const int* in_sizes, int n_in,
                              void* d_out, int out_size, void* d_ws, size_t ws_size,
                              hipStream_t stream) {
    (void)in_sizes; (void)n_in; (void)out_size; (void)ws_size;
    const float* text  = (const float*)d_in[0];
    const float* image = (const float*)d_in[1];
    const int*   maski = (const int*)d_in[2];
    const float* w_qt = (const float*)d_in[3];  const float* b_qt = (const float*)d_in[4];
    const float* w_ki = (const float*)d_in[5];  const float* b_ki = (const float*)d_in[6];
    const float* w_vi = (const float*)d_in[7];  const float* b_vi = (const float*)d_in[8];
    const float* w_qi = (const float*)d_in[9];  const float* b_qi = (const float*)d_in[10];
    const float* w_kt = (const float*)d_in[11]; const float* b_kt = (const float*)d_in[12];
    const float* w_vt = (const float*)d_in[13]; const float* b_vt = (const float*)d_in[14];
    const float* w_ot = (const float*)d_in[15]; const float* b_ot = (const float*)d_in[16];
    const float* w_oi = (const float*)d_in[17]; const float* b_oi = (const float*)d_in[18];

    const int B = 16, T = 512, P = 576, D = 1024;
    const int MT = B * T;   // 8192
    const int MI = B * P;   // 9216

    char* wp = (char*)d_ws;
    auto alloc = [&](size_t bytes) { char* r = wp; wp += (bytes + 255) & ~(size_t)255; return r; };
    u16* Xt    = (u16*)alloc((size_t)MT * D * 2);        // reused as AttT
    u16* Xi    = (u16*)alloc((size_t)MI * D * 2);        // reused as AttI
    u16* Wqk_t = (u16*)alloc((size_t)2 * D * D * 2);
    u16* Wqk_i = (u16*)alloc((size_t)2 * D * D * 2);
    u16* Wv_t  = (u16*)alloc((size_t)D * D * 2);
    u16* Wv_i  = (u16*)alloc((size_t)D * D * 2);
    u16* Wot   = (u16*)alloc((size_t)D * D * 2);
    u16* Woi   = (u16*)alloc((size_t)D * D * 2);
    float* bqk_t = (float*)alloc((size_t)2 * D * 4);
    float* bqk_i = (float*)alloc((size_t)2 * D * 4);
    float* mbf   = (float*)alloc((size_t)B * T * 4);
    u16* QKt  = (u16*)alloc((size_t)2 * MT * D * 2);     // Q_t | K_t head-split
    u16* QKi  = (u16*)alloc((size_t)2 * MI * D * 2);     // Q_i | K_i
    u16* Vtt  = (u16*)alloc((size_t)MT * D * 2);         // [B][16][64][512]
    u16* Vti  = (u16*)alloc((size_t)MI * D * 2);         // [B][16][64][576]

    auto cvt = [&](const float* s, u16* d, size_t n) {
        int n4 = (int)(n / 4);
        cvt_f32_bf16<<<(n4 + 255) / 256, 256, 0, stream>>>(s, d, n4);
    };
    cvt(text, Xt, (size_t)MT * D);
    cvt(image, Xi, (size_t)MI * D);
    cvt(w_qt, Wqk_t,                 (size_t)D * D);
    cvt(w_kt, Wqk_t + (size_t)D * D, (size_t)D * D);
    cvt(w_qi, Wqk_i,                 (size_t)D * D);
    cvt(w_ki, Wqk_i + (size_t)D * D, (size_t)D * D);
    cvt(w_vt, Wv_t, (size_t)D * D);
    cvt(w_vi, Wv_i, (size_t)D * D);
    cvt(w_ot, Wot,  (size_t)D * D);
    cvt(w_oi, Woi,  (size_t)D * D);
    hipMemcpyAsync(bqk_t,     b_qt, D * 4, hipMemcpyDeviceToDevice, stream);
    hipMemcpyAsync(bqk_t + D, b_kt, D * 4, hipMemcpyDeviceToDevice, stream);
    hipMemcpyAsync(bqk_i,     b_qi, D * 4, hipMemcpyDeviceToDevice, stream);
    hipMemcpyAsync(bqk_i + D, b_ki, D * 4, hipMemcpyDeviceToDevice, stream);
    mask_prep<<<(B * T + 255) / 256, 256, 0, stream>>>(maski, mbf, B * T);

    // QK projections -> head-split Q,K
    gemm_bt<1><<<dim3(2 * D / 128, MT / 128), 256, 0, stream>>>(
        Xt, Wqk_t, bqk_t, QKt, MT, 2 * D, D, 0, T, (size_t)MT * D);
    gemm_bt<1><<<dim3(2 * D / 128, MI / 128), 256, 0, stream>>>(
        Xi, Wqk_i, bqk_i, QKi, MI, 2 * D, D, 0, P, (size_t)MI * D);
    // V projections as swapped GEMM -> transposed Vt directly
    gemm_bt<2><<<dim3(MT / 128, D / 128), 256, 0, stream>>>(
        Wv_t, Xt, b_vt, Vtt, D, MT, D, 0, T, 0);
    gemm_bt<2><<<dim3(MI / 128, D / 128), 256, 0, stream>>>(
        Wv_i, Xi, b_vi, Vti, D, MI, D, 0, P, 0);

    // text attends to image (no mask): NQ=8 (Sq=512), SK=576
    attn_v3<0, 8, 576><<<8 * 256, 256, 0, stream>>>(
        QKt, QKi + (size_t)MI * D, Vti, nullptr, Xt);
    // image attends to text (masked): NQ=9 (Sq=576), SK=512
    attn_v3<1, 9, 512><<<9 * 256, 256, 0, stream>>>(
        QKi, QKt + (size_t)MT * D, Vtt, mbf, Xi);

    // output projections (f32 out + bias)
    gemm_bt<0><<<dim3(D / 128, MT / 128), 256, 0, stream>>>(
        Xt, Wot, b_ot, d_out, MT, D, D, D, T, 0);
    gemm_bt<0><<<dim3(D / 128, MI / 128), 256, 0, stream>>>(
        Xi, Woi, b_oi, (void*)((float*)d_out + (size_t)MT * D), MI, D, D, D, P, 0);
}

// Round 4
// 394.666 us; speedup vs baseline: 1.5263x; 1.1589x over previous
//
#include <hip/hip_runtime.h>
#include <stdint.h>

typedef unsigned short u16;
typedef __bf16 bf16x8 __attribute__((ext_vector_type(8)));
typedef float f32x4 __attribute__((ext_vector_type(4)));

#define SCALE_QK 0.125f

__device__ __forceinline__ u16 f2bf(float f) {
    uint32_t u = __builtin_bit_cast(uint32_t, f);
    u += 0x7FFFu + ((u >> 16) & 1u);
    return (u16)(u >> 16);
}

__device__ __forceinline__ int bdiv(int x, int S) {
    return (S == 512) ? (x >> 9) : (int)(((uint64_t)(x >> 6) * 954437177ull) >> 33);
}

// ---------------- f32 -> bf16 convert ----------------
__global__ void cvt_f32_bf16(const float* __restrict__ src, u16* __restrict__ dst, int n4) {
    int i = blockIdx.x * blockDim.x + threadIdx.x;
    if (i >= n4) return;
    float4 v = ((const float4*)src)[i];
    ushort4 o;
    o.x = f2bf(v.x); o.y = f2bf(v.y); o.z = f2bf(v.z); o.w = f2bf(v.w);
    ((ushort4*)dst)[i] = o;
}

// ---------------- mask -> additive f32 bias ----------------
__global__ void mask_prep(const int* __restrict__ maski, float* __restrict__ mb, int n) {
    int i = blockIdx.x * blockDim.x + threadIdx.x;
    if (i >= n) return;
    int v0 = maski[0];
    int v = (v0 == 0x01010101) ? (int)((const unsigned char*)maski)[i] : maski[i];
    mb[i] = v ? 0.0f : -1e30f;
}

// ---------------- GEMM: C = A[M,K] * Bt[N,K]^T + bias (m97 + XCD swizzle) ----------------
__device__ __forceinline__ void gload_lds16(const void* g, void* l) {
    __builtin_amdgcn_global_load_lds(
        (__attribute__((address_space(1))) void*)(g),
        (__attribute__((address_space(3))) void*)(l), 16, 0, 0);
}

template<int LAYOUT>
__global__ __launch_bounds__(256)
void gemm_bt(const u16* __restrict__ A, const u16* __restrict__ Bt,
             const float* __restrict__ bias, void* __restrict__ Cout,
             int nx, int K, int ldc, int S, size_t partStride) {
    __shared__ u16 As[128 * 32];
    __shared__ u16 Bs[128 * 32];
    const int tid = threadIdx.x;
    const int wid = tid >> 6, lane = tid & 63;
    const int lo = lane & 15, hi = lane >> 4;
    const int wr = wid >> 1, wc = wid & 1;
    // XCD-aware bijective swizzle (gridDim.x % 8 == 0 for all our launches)
    const int id = blockIdx.x;
    const int f = (id & 7) * ((int)gridDim.x >> 3) + (id >> 3);
    const int bm = f / nx, bn = f - bm * nx;
    const u16* Ab = A + (size_t)bm * 128 * K;
    const u16* Bb = Bt + (size_t)bn * 128 * K;
    f32x4 acc[4][4] = {};
    for (int k0 = 0; k0 < K; k0 += 32) {
#pragma unroll
        for (int it = 0; it < 2; ++it) {
            int eo = it * 2048 + wid * 512 + lane * 8;
            int row = eo >> 5, kk = eo & 31;
            gload_lds16(Ab + (size_t)row * K + k0 + kk, As + it * 2048 + wid * 512);
            gload_lds16(Bb + (size_t)row * K + k0 + kk, Bs + it * 2048 + wid * 512);
        }
        __syncthreads();
        bf16x8 af[4], bfr[4];
        const int koff = hi * 8;
#pragma unroll
        for (int m = 0; m < 4; ++m)
            af[m] = *(const bf16x8*)(As + (wr * 64 + m * 16 + lo) * 32 + koff);
#pragma unroll
        for (int n = 0; n < 4; ++n)
            bfr[n] = *(const bf16x8*)(Bs + (wc * 64 + n * 16 + lo) * 32 + koff);
        __builtin_amdgcn_s_setprio(1);
#pragma unroll
        for (int m = 0; m < 4; ++m)
#pragma unroll
            for (int n = 0; n < 4; ++n)
                acc[m][n] = __builtin_amdgcn_mfma_f32_16x16x32_bf16(af[m], bfr[n], acc[m][n], 0, 0, 0);
        __builtin_amdgcn_s_setprio(0);
        __syncthreads();
    }
    const int rowbase = bm * 128 + wr * 64, colbase = bn * 128 + wc * 64;

    if (LAYOUT == 0) {
        float* C = (float*)Cout;
#pragma unroll
        for (int m = 0; m < 4; ++m)
#pragma unroll
            for (int r = 0; r < 4; ++r) {
                int row = rowbase + m * 16 + hi * 4 + r;
#pragma unroll
                for (int n = 0; n < 4; ++n) {
                    int col = colbase + n * 16 + lo;
                    C[(size_t)row * ldc + col] = acc[m][n][r] + bias[col];
                }
            }
    } else if (LAYOUT == 1) {
        const int part = colbase >> 10;
        const int h = (colbase >> 6) & 15;
        u16* base = (u16*)Cout + (size_t)part * partStride;
        float bv[4];
#pragma unroll
        for (int n = 0; n < 4; ++n) bv[n] = bias[colbase + n * 16 + lo];
#pragma unroll
        for (int m = 0; m < 4; ++m)
#pragma unroll
            for (int r = 0; r < 4; ++r) {
                int row = rowbase + m * 16 + hi * 4 + r;
                int b = bdiv(row, S);
                int s = row - b * S;
                u16* rp = base + (((size_t)(b * 16 + h) * S + s) << 6);
#pragma unroll
                for (int n = 0; n < 4; ++n)
                    rp[n * 16 + lo] = f2bf(acc[m][n][r] + bv[n]);
            }
    } else {
        u16* base = (u16*)Cout;
        int bn_[4], s0_[4];
#pragma unroll
        for (int n = 0; n < 4; ++n) {
            int col0 = colbase + n * 16;
            int b = bdiv(col0, S);
            bn_[n] = b;
            s0_[n] = col0 - b * S;
        }
#pragma unroll
        for (int m = 0; m < 4; ++m)
#pragma unroll
            for (int r = 0; r < 4; ++r) {
                int dout = rowbase + m * 16 + hi * 4 + r;
                float bv = bias[dout];
                size_t hd = (size_t)(dout >> 6) * 64 + (dout & 63);
#pragma unroll
                for (int n = 0; n < 4; ++n)
                    base[((size_t)(bn_[n] * 16) * 64 + hd) * S + s0_[n] + lo] =
                        f2bf(acc[m][n][r] + bv);
            }
    }
}

// ---------------- fused flash attention v4: swapped operands, lane-local softmax ----------------
// Q,K: [B][H][Sq][64] bf16. Vt: [B][H][64][Sk] bf16. Out merged [B*Sq][1024] bf16.
// S^T = mfma(K,Q): lane lo = q, key = 16*kt + hi*4 + r  -> softmax stats per-lane scalars.
// O^T = mfma(Vt, P^T): lane lo = q, d = 16*n + hi*4 + r -> scalar rescale/normalize.
template<int MASKED, int NQ, int SK>
__global__ __launch_bounds__(256)
void attn_v4(const u16* __restrict__ Q, const u16* __restrict__ Kb,
             const u16* __restrict__ Vt, const float* __restrict__ mb,
             u16* __restrict__ Out) {
    constexpr int SQ = NQ * 64;
    constexpr int NC = SK / 64;
    __shared__ u16 kls[2][64 * 64];
    __shared__ u16 vls[2][64 * 64];
    __shared__ u16 pls[4][16 * 72];
    const int tid = threadIdx.x, wid = tid >> 6, lane = tid & 63;
    const int lo = lane & 15, hi = lane >> 4;
    const int id = blockIdx.x;
    const int f = (id & 7) * (NQ * 32) + (id >> 3);
    const int qc = f % NQ, bh = f / NQ;
    const int b = bh >> 4, h = bh & 15;
    const int q0 = qc * 64 + wid * 16;
    const u16* Qp = Q + ((size_t)bh * SQ + q0) * 64;
    const u16* Kp = Kb + (size_t)bh * SK * 64;
    const u16* Vp = Vt + (size_t)bh * 64 * SK;

    bf16x8 qf[2];
#pragma unroll
    for (int ks = 0; ks < 2; ++ks)
        qf[ks] = *(const bf16x8*)(Qp + lo * 64 + ks * 32 + hi * 8);

    f32x4 oacc[4] = {};              // O^T: oacc[n][r] = O^T[n*16+hi*4+r][q=lo]
    float m = -3e38f, l = 0.f;       // per-lane (q = lo)
    u16* pl = pls[wid];
    uint32_t* pl32 = (uint32_t*)pl;

    auto stage = [&](int bufi, int c0) {
#pragma unroll
        for (int j = 0; j < 2; ++j) {
            const int beta = (j * 4 + wid) * 64 + lane;
            const int row = beta >> 3, slot = beta & 7;
            const int e = (slot ^ (row & 7)) << 3;
            gload_lds16(Kp + (size_t)(c0 + row) * 64 + e,
                        &kls[bufi][0] + (j * 4 + wid) * 512);
            gload_lds16(Vp + (size_t)row * SK + c0 + e,
                        &vls[bufi][0] + (j * 4 + wid) * 512);
        }
    };

    stage(0, 0);
    __syncthreads();

    for (int c = 0; c < NC; ++c) {
        const int c0 = c * 64;
        if (c + 1 < NC) stage((c + 1) & 1, c0 + 64);
        const u16* kb = &kls[c & 1][0];
        const u16* vb = &vls[c & 1][0];

        float sc[4][4];
#pragma unroll
        for (int kt = 0; kt < 4; ++kt) {
            const int krow = kt * 16 + lo;
            const int rx = krow & 7;
            bf16x8 kf0 = *(const bf16x8*)(kb + krow * 64 + ((hi ^ rx) << 3));
            bf16x8 kf1 = *(const bf16x8*)(kb + krow * 64 + (((4 + hi) ^ rx) << 3));
            f32x4 z = {};
            __builtin_amdgcn_s_setprio(1);
            z = __builtin_amdgcn_mfma_f32_16x16x32_bf16(kf0, qf[0], z, 0, 0, 0);
            z = __builtin_amdgcn_mfma_f32_16x16x32_bf16(kf1, qf[1], z, 0, 0, 0);
            __builtin_amdgcn_s_setprio(0);
            if (MASKED) {
                float4 mv = *(const float4*)(mb + b * SK + c0 + kt * 16 + hi * 4);
#pragma unroll
                for (int r = 0; r < 4; ++r) sc[kt][r] = z[r] * SCALE_QK + ((const float*)&mv)[r];
            } else {
#pragma unroll
                for (int r = 0; r < 4; ++r) sc[kt][r] = z[r] * SCALE_QK;
            }
        }
        // per-lane max over 16, then across hi groups (2 shuffles)
        float a0 = fmaxf(fmaxf(sc[0][0], sc[0][1]), fmaxf(sc[0][2], sc[0][3]));
        float a1 = fmaxf(fmaxf(sc[1][0], sc[1][1]), fmaxf(sc[1][2], sc[1][3]));
        float a2 = fmaxf(fmaxf(sc[2][0], sc[2][1]), fmaxf(sc[2][2], sc[2][3]));
        float a3 = fmaxf(fmaxf(sc[3][0], sc[3][1]), fmaxf(sc[3][2], sc[3][3]));
        float pmax = fmaxf(fmaxf(a0, a1), fmaxf(a2, a3));
        pmax = fmaxf(pmax, __shfl_xor(pmax, 16));
        pmax = fmaxf(pmax, __shfl_xor(pmax, 32));
        // defer-max (T13): only rescale when the max moved by > 8
        if (!__all(pmax - m <= 8.0f)) {
            float mn = fmaxf(m, pmax);
            float alpha = __expf(m - mn);
            m = mn;
            l *= alpha;
#pragma unroll
            for (int n = 0; n < 4; ++n)
#pragma unroll
                for (int r = 0; r < 4; ++r) oacc[n][r] *= alpha;
        }
        float sum = 0.f;
#pragma unroll
        for (int kt = 0; kt < 4; ++kt) {
#pragma unroll
            for (int r = 0; r < 4; ++r) {
                float p = __expf(sc[kt][r] - m);
                sc[kt][r] = p;
                sum += p;
            }
        }
        sum += __shfl_xor(sum, 16);
        sum += __shfl_xor(sum, 32);
        l += sum;
        // P^T -> LDS as P[q][key], bf16-pair packed: 8 x ds_write_b32
#pragma unroll
        for (int kt = 0; kt < 4; ++kt) {
#pragma unroll
            for (int rp = 0; rp < 2; ++rp) {
                uint32_t w = (uint32_t)f2bf(sc[kt][2 * rp]) |
                             ((uint32_t)f2bf(sc[kt][2 * rp + 1]) << 16);
                pl32[lo * 36 + kt * 8 + hi * 2 + rp] = w;
            }
        }
        bf16x8 pf0 = *(const bf16x8*)(pl + lo * 72 + hi * 8);
        bf16x8 pf1 = *(const bf16x8*)(pl + lo * 72 + 32 + hi * 8);
        __builtin_amdgcn_s_setprio(1);
#pragma unroll
        for (int n = 0; n < 4; ++n) {
            const int d = n * 16 + lo;
            const int dx = d & 7;
            bf16x8 v0 = *(const bf16x8*)(vb + d * 64 + ((hi ^ dx) << 3));
            bf16x8 v1 = *(const bf16x8*)(vb + d * 64 + (((4 + hi) ^ dx) << 3));
            oacc[n] = __builtin_amdgcn_mfma_f32_16x16x32_bf16(v0, pf0, oacc[n], 0, 0, 0);
            oacc[n] = __builtin_amdgcn_mfma_f32_16x16x32_bf16(v1, pf1, oacc[n], 0, 0, 0);
        }
        __builtin_amdgcn_s_setprio(0);
        __syncthreads();
    }
    const float inv = 1.0f / l;
    // lane lo = q-row; writes 4 contiguous bf16 per n at col 16n + 4hi
    u16* op = Out + ((size_t)(b * SQ + q0 + lo)) * 1024 + h * 64;
#pragma unroll
    for (int n = 0; n < 4; ++n) {
        ushort4 w;
        w.x = f2bf(oacc[n][0] * inv);
        w.y = f2bf(oacc[n][1] * inv);
        w.z = f2bf(oacc[n][2] * inv);
        w.w = f2bf(oacc[n][3] * inv);
        *(ushort4*)(op + n * 16 + hi * 4) = w;
    }
}

// ---------------- host ----------------
extern "C" void kernel_launch(void* const* d_in, const int* in_sizes, int n_in,
                              void* d_out, int out_size, void* d_ws, size_t ws_size,
                              hipStream_t stream) {
    (void)in_sizes; (void)n_in; (void)out_size; (void)ws_size;
    const float* text  = (const float*)d_in[0];
    const float* image = (const float*)d_in[1];
    const int*   maski = (const int*)d_in[2];
    const float* w_qt = (const float*)d_in[3];  const float* b_qt = (const float*)d_in[4];
    const float* w_ki = (const float*)d_in[5];  const float* b_ki = (const float*)d_in[6];
    const float* w_vi = (const float*)d_in[7];  const float* b_vi = (const float*)d_in[8];
    const float* w_qi = (const float*)d_in[9];  const float* b_qi = (const float*)d_in[10];
    const float* w_kt = (const float*)d_in[11]; const float* b_kt = (const float*)d_in[12];
    const float* w_vt = (const float*)d_in[13]; const float* b_vt = (const float*)d_in[14];
    const float* w_ot = (const float*)d_in[15]; const float* b_ot = (const float*)d_in[16];
    const float* w_oi = (const float*)d_in[17]; const float* b_oi = (const float*)d_in[18];

    const int B = 16, T = 512, P = 576, D = 1024;
    const int MT = B * T;   // 8192
    const int MI = B * P;   // 9216

    char* wp = (char*)d_ws;
    auto alloc = [&](size_t bytes) { char* r = wp; wp += (bytes + 255) & ~(size_t)255; return r; };
    u16* Xt    = (u16*)alloc((size_t)MT * D * 2);        // reused as AttT
    u16* Xi    = (u16*)alloc((size_t)MI * D * 2);        // reused as AttI
    u16* Wqk_t = (u16*)alloc((size_t)2 * D * D * 2);
    u16* Wqk_i = (u16*)alloc((size_t)2 * D * D * 2);
    u16* Wv_t  = (u16*)alloc((size_t)D * D * 2);
    u16* Wv_i  = (u16*)alloc((size_t)D * D * 2);
    u16* Wot   = (u16*)alloc((size_t)D * D * 2);
    u16* Woi   = (u16*)alloc((size_t)D * D * 2);
    float* bqk_t = (float*)alloc((size_t)2 * D * 4);
    float* bqk_i = (float*)alloc((size_t)2 * D * 4);
    float* mbf   = (float*)alloc((size_t)B * T * 4);
    u16* QKt  = (u16*)alloc((size_t)2 * MT * D * 2);     // Q_t | K_t head-split
    u16* QKi  = (u16*)alloc((size_t)2 * MI * D * 2);     // Q_i | K_i
    u16* Vtt  = (u16*)alloc((size_t)MT * D * 2);         // [B][16][64][512]
    u16* Vti  = (u16*)alloc((size_t)MI * D * 2);         // [B][16][64][576]

    auto cvt = [&](const float* s, u16* d, size_t n) {
        int n4 = (int)(n / 4);
        cvt_f32_bf16<<<(n4 + 255) / 256, 256, 0, stream>>>(s, d, n4);
    };
    cvt(text, Xt, (size_t)MT * D);
    cvt(image, Xi, (size_t)MI * D);
    cvt(w_qt, Wqk_t,                 (size_t)D * D);
    cvt(w_kt, Wqk_t + (size_t)D * D, (size_t)D * D);
    cvt(w_qi, Wqk_i,                 (size_t)D * D);
    cvt(w_ki, Wqk_i + (size_t)D * D, (size_t)D * D);
    cvt(w_vt, Wv_t, (size_t)D * D);
    cvt(w_vi, Wv_i, (size_t)D * D);
    cvt(w_ot, Wot,  (size_t)D * D);
    cvt(w_oi, Woi,  (size_t)D * D);
    hipMemcpyAsync(bqk_t,     b_qt, D * 4, hipMemcpyDeviceToDevice, stream);
    hipMemcpyAsync(bqk_t + D, b_kt, D * 4, hipMemcpyDeviceToDevice, stream);
    hipMemcpyAsync(bqk_i,     b_qi, D * 4, hipMemcpyDeviceToDevice, stream);
    hipMemcpyAsync(bqk_i + D, b_ki, D * 4, hipMemcpyDeviceToDevice, stream);
    mask_prep<<<(B * T + 255) / 256, 256, 0, stream>>>(maski, mbf, B * T);

    // QK projections -> head-split Q,K
    gemm_bt<1><<<(2 * D / 128) * (MT / 128), 256, 0, stream>>>(
        Xt, Wqk_t, bqk_t, QKt, 2 * D / 128, D, 0, T, (size_t)MT * D);
    gemm_bt<1><<<(2 * D / 128) * (MI / 128), 256, 0, stream>>>(
        Xi, Wqk_i, bqk_i, QKi, 2 * D / 128, D, 0, P, (size_t)MI * D);
    // V projections as swapped GEMM -> transposed Vt directly
    gemm_bt<2><<<(MT / 128) * (D / 128), 256, 0, stream>>>(
        Wv_t, Xt, b_vt, Vtt, MT / 128, D, 0, T, 0);
    gemm_bt<2><<<(MI / 128) * (D / 128), 256, 0, stream>>>(
        Wv_i, Xi, b_vi, Vti, MI / 128, D, 0, P, 0);

    // text attends to image (no mask): NQ=8 (Sq=512), SK=576
    attn_v4<0, 8, 576><<<8 * 256, 256, 0, stream>>>(
        QKt, QKi + (size_t)MI * D, Vti, nullptr, Xt);
    // image attends to text (masked): NQ=9 (Sq=576), SK=512
    attn_v4<1, 9, 512><<<9 * 256, 256, 0, stream>>>(
        QKi, QKt + (size_t)MT * D, Vtt, mbf, Xi);

    // output projections (f32 out + bias)
    gemm_bt<0><<<(D / 128) * (MT / 128), 256, 0, stream>>>(
        Xt, Wot, b_ot, d_out, D / 128, D, D, T, 0);
    gemm_bt<0><<<(D / 128) * (MI / 128), 256, 0, stream>>>(
        Xi, Woi, b_oi, (void*)((float*)d_out + (size_t)MT * D), D / 128, D, D, P, 0);
}